// Round 17
// baseline (208.978 us; speedup 1.0000x reference)
//
#include <hip/hip_runtime.h>
#include <hip/hip_bf16.h>

#define BATCH 8
#define V 2048
#define H 256
#define D 128
#define NPROJ 512  // proj blocks come first in k_prep's grid

typedef __attribute__((ext_vector_type(8))) _Float16 f16x8;
typedef __attribute__((ext_vector_type(4))) float f32x4;
typedef unsigned int uint32;

static __device__ __forceinline__ uint32 pk2(float lo, float hi) {
  __fp16 __attribute__((ext_vector_type(2))) h = __builtin_amdgcn_cvt_pkrtz(lo, hi);
  uint32 u;
  __builtin_memcpy(&u, &h, 4);
  return u;
}

// ================= shared proj/pack body (used by k_prep and k_prep_p3) =================
#define PREP_BODY(x, adj, W, a, pTf, ei, Fh, Ph, pkT)                                      \
  if (blockIdx.x >= NPROJ) {                                                               \
    const int i = blockIdx.x - NPROJ;                                                      \
    const int* row = adj + (size_t)i * V;                                                  \
    _Pragma("unroll") for (int it = 0; it < 8; ++it) {                                     \
      const int j = it * 256 + wave * 64 + lane;                                           \
      unsigned long long m = __ballot(row[j] != 0);                                        \
      if (lane < 2) {                                                                      \
        const int jw = it * 8 + wave * 2 + lane;                                           \
        pkT[(size_t)jw * V + i] = (unsigned int)(m >> (lane * 32));                        \
      }                                                                                    \
    }                                                                                      \
  } else {                                                                                 \
    const int b = blockIdx.x >> 6;                                                         \
    const int jt0 = blockIdx.x & 63;                                                       \
    const int j0 = jt0 * 32;                                                               \
    const int kq = lane >> 4, l15 = lane & 15;                                             \
    {                                                                                      \
      float sL = 0.f, sR = 0.f;                                                            \
      for (int d = 0; d < D; ++d) {                                                        \
        const float wv = W[(size_t)d * H + t];                                             \
        sL += wv * a[d];                                                                   \
        sR += wv * a[D + d];                                                               \
      }                                                                                    \
      vls[t] = sL;                                                                         \
      vrs[t] = sR;                                                                         \
    }                                                                                      \
    __syncthreads();                                                                       \
    {                                                                                      \
      const float4 vl4 = *(const float4*)(vls + lane * 4);                                 \
      const float4 vr4 = *(const float4*)(vrs + lane * 4);                                 \
      _Pragma("unroll") for (int rr = 0; rr < 8; ++rr) {                                   \
        const int row = wave * 8 + rr;                                                     \
        const float4 xv = *(const float4*)(x + ((size_t)(b * V + j0 + row)) * H + lane * 4); \
        uint32 u0 = pk2(xv.x, xv.y), u1 = pk2(xv.z, xv.w);                                 \
        const int off = row * 512 + ((lane * 8) ^ ((row & 7) << 4));                       \
        *(uint32*)(xls + off) = u0;                                                        \
        *(uint32*)(xls + off + 4) = u1;                                                    \
        float eL = xv.x * vl4.x + xv.y * vl4.y + xv.z * vl4.z + xv.w * vl4.w;              \
        float eR = xv.x * vr4.x + xv.y * vr4.y + xv.z * vr4.z + xv.w * vr4.w;              \
        _Pragma("unroll") for (int off_ = 1; off_ < 64; off_ <<= 1) {                      \
          eL += __shfl_xor(eL, off_, 64);                                                  \
          eR += __shfl_xor(eR, off_, 64);                                                  \
        }                                                                                  \
        if (lane == 0) {                                                                   \
          const size_t r_ = (size_t)b * V + j0 + row;                                      \
          ei[r_] = eL;                                                                     \
          Fh[r_] = (_Float16)__expf(eR);                                                   \
          Ph[r_] = (_Float16)__expf(0.2f * eR);                                            \
        }                                                                                  \
      }                                                                                    \
    }                                                                                      \
    __syncthreads();                                                                       \
    f32x4 acc[2][2];                                                                       \
    _Pragma("unroll") for (int i_ = 0; i_ < 2; ++i_)                                       \
      _Pragma("unroll") for (int j_ = 0; j_ < 2; ++j_)                                     \
        acc[i_][j_] = (f32x4){0.f, 0.f, 0.f, 0.f};                                         \
    typedef union { uint32 u[4]; f16x8 v; } AFu_;                                          \
    const float* wrow0 = W + (size_t)(wave * 32 + l15) * H + kq * 8;                       \
    const float* wrow1 = wrow0 + 16 * H;                                                   \
    _Pragma("unroll") for (int ks = 0; ks < 8; ++ks) {                                     \
      const int ho = ks * 32;                                                              \
      const float4 w0a = *(const float4*)(wrow0 + ho), w0b = *(const float4*)(wrow0 + ho + 4); \
      const float4 w1a = *(const float4*)(wrow1 + ho), w1b = *(const float4*)(wrow1 + ho + 4); \
      AFu_ aw0, aw1;                                                                       \
      aw0.u[0] = pk2(w0a.x, w0a.y); aw0.u[1] = pk2(w0a.z, w0a.w);                          \
      aw0.u[2] = pk2(w0b.x, w0b.y); aw0.u[3] = pk2(w0b.z, w0b.w);                          \
      aw1.u[0] = pk2(w1a.x, w1a.y); aw1.u[1] = pk2(w1a.z, w1a.w);                          \
      aw1.u[2] = pk2(w1b.x, w1b.y); aw1.u[3] = pk2(w1b.z, w1b.w);                          \
      f16x8 bx[2];                                                                         \
      _Pragma("unroll") for (int jt = 0; jt < 2; ++jt) {                                   \
        const int row = jt * 16 + l15;                                                     \
        bx[jt] = *(const f16x8*)(xls + row * 512 + ((ks * 64 + kq * 16) ^ ((l15 & 7) << 4))); \
      }                                                                                    \
      acc[0][0] = __builtin_amdgcn_mfma_f32_16x16x32_f16(aw0.v, bx[0], acc[0][0], 0, 0, 0); \
      acc[0][1] = __builtin_amdgcn_mfma_f32_16x16x32_f16(aw0.v, bx[1], acc[0][1], 0, 0, 0); \
      acc[1][0] = __builtin_amdgcn_mfma_f32_16x16x32_f16(aw1.v, bx[0], acc[1][0], 0, 0, 0); \
      acc[1][1] = __builtin_amdgcn_mfma_f32_16x16x32_f16(aw1.v, bx[1], acc[1][1], 0, 0, 0); \
    }                                                                                      \
    _Pragma("unroll") for (int t_ = 0; t_ < 2; ++t_)                                       \
      _Pragma("unroll") for (int jt = 0; jt < 2; ++jt)                                     \
        _Pragma("unroll") for (int r = 0; r < 4; ++r)                                      \
          st[(wave * 2 + t_) * 16 + kq * 4 + r][jt * 16 + l15] = (_Float16)acc[t_][jt][r]; \
    __syncthreads();                                                                       \
    const int c = jt0 >> 1;                                                                \
    const int ksh = jt0 & 1;                                                               \
    const int g = t >> 6;                                                                  \
    _Pragma("unroll") for (int ff = 0; ff < 2; ++ff) {                                     \
      const int dt = ff * 4 + g;                                                           \
      const int dR = dt * 16 + l15;                                                        \
      const int jc = kq * 8;                                                               \
      union { unsigned long long ll[2]; f16x8 v; } vv_;                                    \
      vv_.ll[0] = *(const unsigned long long*)&st[dR][jc];                                 \
      vv_.ll[1] = *(const unsigned long long*)&st[dR][jc + 4];                             \
      *(f16x8*)((char*)pTf +                                                               \
                (((((size_t)b * 32 + c) * 8 + dt) * 2 + ksh) * 64 + lane) * 16) = vv_.v;   \
    }                                                                                      \
  }

__global__ __launch_bounds__(256, 2) void k_prep(const float* __restrict__ x,
                                                 const int* __restrict__ adj,
                                                 const float* __restrict__ W,
                                                 const float* __restrict__ a,
                                                 _Float16* __restrict__ pTf,
                                                 float* __restrict__ ei,
                                                 _Float16* __restrict__ Fh,
                                                 _Float16* __restrict__ Ph,
                                                 unsigned int* __restrict__ pkT) {
  __shared__ char xls[32 * 512];
  __shared__ _Float16 st[128][52];
  __shared__ float vls[256], vrs[256];
  const int t = threadIdx.x, lane = t & 63, wave = t >> 6;
  PREP_BODY(x, adj, W, a, pTf, ei, Fh, Ph, pkT)
}

// probe: same work x3 into scratch
__global__ __launch_bounds__(256, 2) void k_prep_p3(const float* __restrict__ x,
                                                    const int* __restrict__ adj,
                                                    const float* __restrict__ W,
                                                    const float* __restrict__ a,
                                                    _Float16* __restrict__ pTf,
                                                    float* __restrict__ ei,
                                                    _Float16* __restrict__ Fh,
                                                    _Float16* __restrict__ Ph,
                                                    unsigned int* __restrict__ pkT) {
  __shared__ char xls[32 * 512];
  __shared__ _Float16 st[128][52];
  __shared__ float vls[256], vrs[256];
  const int t = threadIdx.x, lane = t & 63, wave = t >> 6;
  for (int rep = 0; rep < 3; ++rep) {
    PREP_BODY(x, adj, W, a, pTf, ei, Fh, Ph, pkT)
    __syncthreads();
  }
}

// ================= k_attn (verified 54.4/51.8-us version) =================
typedef union { uint4 v; uint32 u[4]; } U4;
typedef union { uint32 u[4]; f16x8 v; } AFu;
struct PFS {
  U4 FH0, FH1, PH0, PH1;
  uint32 w[2][2];
  AFu AF[2][2];
};

#define PKMUL(d, a, b) asm("v_pk_mul_f16 %0, %1, %2" : "=v"(d) : "v"(a), "v"(b));
#define PKMAX(d, a, b) asm("v_pk_max_f16 %0, %1, %2" : "=v"(d) : "v"(a), "v"(b));

#define WGEN(S)                                                        \
  _Pragma("unroll") for (int ig_ = 0; ig_ < 2; ++ig_) {                \
    const uint32 E2_ = Ei2g[ig_], EP2_ = Eip2g[ig_];                   \
    _Pragma("unroll") for (int ks_ = 0; ks_ < 2; ++ks_) {              \
      const uint32 sh_ = (S).w[ig_][ks_] >> kq8;                       \
      _Pragma("unroll") for (int p_ = 0; p_ < 4; ++p_) {               \
        uint32 t0_, t1_;                                               \
        PKMUL(t0_, E2_, (ks_ ? (S).FH1 : (S).FH0).u[p_])               \
        PKMUL(t1_, EP2_, (ks_ ? (S).PH1 : (S).PH0).u[p_])              \
        PKMAX(t0_, t0_, t1_)                                           \
        const uint32 m_ = ((sh_ << (14 - 2 * p_)) & 0x4000u) |         \
                          ((sh_ << (29 - 2 * p_)) & 0x40000000u);      \
        PKMUL((S).AF[ig_][ks_].u[p_], t0_, m_)                         \
      }                                                                \
    }                                                                  \
  }

#define PFETCH(S, C)                                       \
  {                                                        \
    const char* f_ = fbase + (C) * 128 + kq16;             \
    const char* p_ = pbase + (C) * 128 + kq16;             \
    (S).FH0.v = *(const uint4*)(f_);                       \
    (S).FH1.v = *(const uint4*)(f_ + 64);                  \
    (S).PH0.v = *(const uint4*)(p_);                       \
    (S).PH1.v = *(const uint4*)(p_ + 64);                  \
    (S).w[0][0] = adjpT[(size_t)((C) * 2) * V + iR0];      \
    (S).w[0][1] = adjpT[(size_t)((C) * 2 + 1) * V + iR0];  \
    (S).w[1][0] = adjpT[(size_t)((C) * 2) * V + iR1];      \
    (S).w[1][1] = adjpT[(size_t)((C) * 2 + 1) * V + iR1];  \
  }

// opaque replacement: no loads, same downstream VALU (each word made a distinct unknown)
#define OPQ(x) asm("" : "+v"(x));
#define PFETCH_OPQ(S)                                          \
  {                                                            \
    uint32 c_ = 0x3C003C00u, w_ = 0x5A5A5A5Au;                 \
    OPQ(c_) OPQ(w_)                                            \
    _Pragma("unroll") for (int p_ = 0; p_ < 4; ++p_) {         \
      (S).FH0.u[p_] = c_; OPQ((S).FH0.u[p_])                   \
      (S).FH1.u[p_] = c_; OPQ((S).FH1.u[p_])                   \
      (S).PH0.u[p_] = c_; OPQ((S).PH0.u[p_])                   \
      (S).PH1.u[p_] = c_; OPQ((S).PH1.u[p_])                   \
    }                                                          \
    (S).w[0][0] = w_; OPQ((S).w[0][0])                         \
    (S).w[0][1] = w_; OPQ((S).w[0][1])                         \
    (S).w[1][0] = w_; OPQ((S).w[1][0])                         \
    (S).w[1][1] = w_; OPQ((S).w[1][1])                         \
  }

#define LOADB(BR, C)                                      \
  {                                                       \
    const char* g_ = gbase + (size_t)(C) * 16384;         \
    _Pragma("unroll") for (int q_ = 0; q_ < 4; ++q_)      \
      BR[q_] = *(const f16x8*)(g_ + q_ * 1024);           \
  }

#define DOMFMA(S, BX)                                                          \
  _Pragma("unroll") for (int ig_ = 0; ig_ < 2; ++ig_)                          \
    _Pragma("unroll") for (int nt_ = 0; nt_ < 2; ++nt_)                        \
      _Pragma("unroll") for (int ks_ = 0; ks_ < 2; ++ks_)                      \
        acc[ig_][nt_][ks_] = __builtin_amdgcn_mfma_f32_16x16x32_f16(           \
            (S).AF[ig_][ks_].v, BX[nt_ * 2 + ks_], acc[ig_][nt_][ks_], 0, 0, 0); \
  _Pragma("unroll") for (int ig_ = 0; ig_ < 2; ++ig_)                          \
    _Pragma("unroll") for (int ks_ = 0; ks_ < 2; ++ks_)                        \
      accS[ig_][ks_] = __builtin_amdgcn_mfma_f32_16x16x32_f16(                 \
          (S).AF[ig_][ks_].v, onesv, accS[ig_][ks_], 0, 0, 0);

#define BODYF(C, SX, BX, SY)   \
  {                            \
    DOMFMA(SX, BX)             \
    WGEN(SY)                   \
    LOADB(BX, (C) + 2)         \
    PFETCH(SX, (C) + 2)        \
  }

#define BODYF_OPQ(C, SX, BX, SY)  \
  {                               \
    DOMFMA(SX, BX)                \
    WGEN(SY)                      \
    LOADB(BX, (C) + 2)            \
    PFETCH_OPQ(SX)                \
  }

// common pre-amble for all attn kernels
#define ATTN_SETUP                                                             \
  const int t = threadIdx.x, lane = t & 63, wave = t >> 6;                     \
  const int ih = wave >> 1;                                                    \
  const int dq = wave & 1;                                                     \
  const int pay = (blockIdx.x & 7) * 64 + (blockIdx.x >> 3);                   \
  const int bdh = pay >> 4;                                                    \
  const int itl = pay & 15;                                                    \
  const int b = bdh >> 2, dh = (bdh >> 1) & 1;                                 \
  const int it = ((bdh & 1) << 4) | itl;                                       \
  const int i0b = it * 64;                                                     \
  const int kq = lane >> 4;                                                    \
  const int kq8 = kq * 8;                                                      \
  const int kq16 = kq * 16;                                                    \
  const int l15 = lane & 15;                                                   \
  const int ibase = i0b + ih * 32;                                             \
  const int iR0 = ibase + l15;                                                 \
  const int iR1 = iR0 + 16;                                                    \
  const float eiv0 = ei[(size_t)b * V + iR0];                                  \
  const float eiv1 = ei[(size_t)b * V + iR1];                                  \
  uint32 Ei2g[2], Eip2g[2];                                                    \
  {                                                                            \
    const float e0 = 0.5f * __expf(eiv0), e1 = 0.5f * __expf(eiv1);            \
    const float p0 = 0.5f * __expf(0.2f * eiv0), p1 = 0.5f * __expf(0.2f * eiv1); \
    Ei2g[0] = pk2(e0, e0); Ei2g[1] = pk2(e1, e1);                              \
    Eip2g[0] = pk2(p0, p0); Eip2g[1] = pk2(p1, p1);                            \
  }                                                                            \
  const char* fbase = (const char*)(Fht + (size_t)b * V);                      \
  const char* pbase = (const char*)(Pht + (size_t)b * V);                      \
  const size_t fb0 = ((size_t)b * 32) * 16384 + (size_t)dh * 8192;             \
  const char* gbase = (const char*)pTf + fb0 + dq * 4096 + lane * 16;          \
  union { uint32 u[4]; f16x8 v; } ones_;                                       \
  ones_.u[0] = ones_.u[1] = ones_.u[2] = ones_.u[3] = 0x3C003C00u;             \
  const f16x8 onesv = ones_.v;

#define ATTN_ACC_INIT                                                          \
  f32x4 acc[2][2][2];                                                          \
  _Pragma("unroll") for (int a_ = 0; a_ < 2; ++a_)                             \
    _Pragma("unroll") for (int b_ = 0; b_ < 2; ++b_)                           \
      _Pragma("unroll") for (int c_ = 0; c_ < 2; ++c_)                         \
        acc[a_][b_][c_] = (f32x4){0.f, 0.f, 0.f, 0.f};                         \
  f32x4 accS[2][2];                                                            \
  _Pragma("unroll") for (int a_ = 0; a_ < 2; ++a_)                             \
    _Pragma("unroll") for (int c_ = 0; c_ < 2; ++c_)                           \
      accS[a_][c_] = (f32x4){0.f, 0.f, 0.f, 0.f};

#define ATTN_EPILOGUE(dst)                                                     \
  float* ob = dst + ((size_t)b * V + ibase) * D + dh * 64 + dq * 32 + l15;     \
  _Pragma("unroll") for (int ig = 0; ig < 2; ++ig) {                           \
    _Pragma("unroll") for (int r = 0; r < 4; ++r) {                            \
      const float inv_ = 1.0f / (accS[ig][0][r] + accS[ig][1][r]);             \
      _Pragma("unroll") for (int nt = 0; nt < 2; ++nt) {                       \
        const float v = (acc[ig][nt][0][r] + acc[ig][nt][1][r]) * inv_;        \
        ob[(size_t)(ig * 16 + kq * 4 + r) * D + nt * 16] = fmaxf(v, 0.f);      \
      }                                                                        \
    }                                                                          \
  }

__global__ __launch_bounds__(256, 2) void k_attn(
    const _Float16* __restrict__ pTf, const float* __restrict__ ei,
    const _Float16* __restrict__ Fht, const _Float16* __restrict__ Pht,
    const unsigned int* __restrict__ adjpT, float* __restrict__ out) {
  ATTN_SETUP
  ATTN_ACC_INIT
  f16x8 bA[4], bB[4];
  PFS sA, sB;
  LOADB(bA, 0)
  LOADB(bB, 1)
  PFETCH(sA, 0)
  PFETCH(sB, 1)
  WGEN(sA)
  for (int c2 = 0; c2 < 15; ++c2) {
    const int c = c2 * 2;
    BODYF(c, sA, bA, sB)
    BODYF(c + 1, sB, bB, sA)
  }
  { DOMFMA(sA, bA) WGEN(sB) }
  { DOMFMA(sB, bB) }
  ATTN_EPILOGUE(out)
}

// probe A: same work x3 into scratch
__global__ __launch_bounds__(256, 2) void k_attn_pA(
    const _Float16* __restrict__ pTf, const float* __restrict__ ei,
    const _Float16* __restrict__ Fht, const _Float16* __restrict__ Pht,
    const unsigned int* __restrict__ adjpT, float* __restrict__ out) {
  ATTN_SETUP
  for (int rep = 0; rep < 3; ++rep) {
    ATTN_ACC_INIT
    f16x8 bA[4], bB[4];
    PFS sA, sB;
    LOADB(bA, 0)
    LOADB(bB, 1)
    PFETCH(sA, 0)
    PFETCH(sB, 1)
    WGEN(sA)
    for (int c2 = 0; c2 < 15; ++c2) {
      const int c = c2 * 2;
      BODYF(c, sA, bA, sB)
      BODYF(c + 1, sB, bB, sA)
    }
    { DOMFMA(sA, bA) WGEN(sB) }
    { DOMFMA(sB, bB) }
    ATTN_EPILOGUE(out)
  }
}

// probe B: x3, F/P/adj loads ablated (opaque regs), B-loads/WGEN/MFMA kept
__global__ __launch_bounds__(256, 2) void k_attn_pB(
    const _Float16* __restrict__ pTf, const float* __restrict__ ei,
    const _Float16* __restrict__ Fht, const _Float16* __restrict__ Pht,
    const unsigned int* __restrict__ adjpT, float* __restrict__ out) {
  ATTN_SETUP
  (void)fbase; (void)pbase; (void)iR1;
  for (int rep = 0; rep < 3; ++rep) {
    ATTN_ACC_INIT
    f16x8 bA[4], bB[4];
    PFS sA, sB;
    LOADB(bA, 0)
    LOADB(bB, 1)
    PFETCH_OPQ(sA)
    PFETCH_OPQ(sB)
    WGEN(sA)
    for (int c2 = 0; c2 < 15; ++c2) {
      const int c = c2 * 2;
      BODYF_OPQ(c, sA, bA, sB)
      BODYF_OPQ(c + 1, sB, bB, sA)
    }
    { DOMFMA(sA, bA) WGEN(sB) }
    { DOMFMA(sB, bB) }
    ATTN_EPILOGUE(out)
  }
}

extern "C" void kernel_launch(void* const* d_in, const int* in_sizes, int n_in,
                              void* d_out, int out_size, void* d_ws, size_t ws_size,
                              hipStream_t stream) {
  const float* x = (const float*)d_in[0];
  const int* adj = (const int*)d_in[1];
  const float* W = (const float*)d_in[2];
  const float* a = (const float*)d_in[3];
  float* out = (float*)d_out;

  char* ws = (char*)d_ws;
  _Float16* pTf = (_Float16*)ws;                                   // 4 MB
  float* ei = (float*)(ws + (4u << 20));                           // 64 KB
  _Float16* Fh = (_Float16*)(ws + (4u << 20) + 65536);             // 32 KB
  _Float16* Ph = (_Float16*)(ws + (4u << 20) + 98304);             // 32 KB
  unsigned int* adjpT = (unsigned int*)(ws + (4u << 20) + 131072); // 512 KB
  // probe scratch
  _Float16* pTf_s = (_Float16*)(ws + (5u << 20));
  float* ei_s = (float*)(ws + (9u << 20));
  _Float16* Fh_s = (_Float16*)(ws + (9u << 20) + 65536);
  _Float16* Ph_s = (_Float16*)(ws + (9u << 20) + 98304);
  unsigned int* adjpT_s = (unsigned int*)(ws + (9u << 20) + 131072);
  float* out_s = (float*)(ws + (10u << 20));                       // 8 MB

  // real pipeline (unchanged from R16 best)
  k_prep<<<dim3(NPROJ + V), dim3(256), 0, stream>>>(x, adj, W, a, pTf, ei, Fh, Ph, adjpT);
  k_attn<<<dim3(BATCH * 2 * (V / 64)), dim3(256), 0, stream>>>(pTf, ei, Fh, Ph, adjpT, out);
  // measurement probes (3x work each, scratch outputs)
  k_prep_p3<<<dim3(NPROJ + V), dim3(256), 0, stream>>>(x, adj, W, a, pTf_s, ei_s, Fh_s, Ph_s, adjpT_s);
  k_attn_pA<<<dim3(BATCH * 2 * (V / 64)), dim3(256), 0, stream>>>(pTf, ei, Fh, Ph, adjpT, out_s);
  k_attn_pB<<<dim3(BATCH * 2 * (V / 64)), dim3(256), 0, stream>>>(pTf, ei, Fh, Ph, adjpT, out_s);
}

// Round 18
// 50.350 us; speedup vs baseline: 4.1505x; 4.1505x over previous
//
#include <hip/hip_runtime.h>
#include <hip/hip_bf16.h>

#define BATCH 8
#define V 2048
#define H 256
#define D 128
#define NPROJ 512  // proj blocks come first in k_prep's grid

typedef __attribute__((ext_vector_type(8))) _Float16 f16x8;
typedef __attribute__((ext_vector_type(2))) _Float16 h2;
typedef __attribute__((ext_vector_type(4))) float f32x4;
typedef unsigned int uint32;

static __device__ __forceinline__ uint32 pk2(float lo, float hi) {
  __fp16 __attribute__((ext_vector_type(2))) h = __builtin_amdgcn_cvt_pkrtz(lo, hi);
  uint32 u;
  __builtin_memcpy(&u, &h, 4);
  return u;
}
static __device__ __forceinline__ h2 u2h(uint32 u) {
  h2 r;
  __builtin_memcpy(&r, &u, 4);
  return r;
}
static __device__ __forceinline__ uint32 h2u(h2 h) {
  uint32 r;
  __builtin_memcpy(&r, &h, 4);
  return r;
}

// -------- K_prep: [blk<512] p-GEMM + e/F/P tables; [blk>=512] adj bit-pack --------
__global__ __launch_bounds__(256, 2) void k_prep(const float* __restrict__ x,
                                                 const int* __restrict__ adj,
                                                 const float* __restrict__ W,
                                                 const float* __restrict__ a,
                                                 _Float16* __restrict__ pTf,
                                                 float* __restrict__ ei,
                                                 _Float16* __restrict__ Fh,
                                                 _Float16* __restrict__ Ph,
                                                 unsigned int* __restrict__ pkT) {
  __shared__ char xls[32 * 512];        // 16 KB: 32 j-rows x 256 h f16, XOR-swizzled
  __shared__ _Float16 st[128][52];      // 13 KB transpose staging
  __shared__ float vls[256], vrs[256];  // 2 KB: vL/vR = W^T aL/aR
  const int t = threadIdx.x, lane = t & 63, wave = t >> 6;

  if (blockIdx.x >= NPROJ) {
    // ---- adj pack block ----
    const int i = blockIdx.x - NPROJ;
    const int* row = adj + (size_t)i * V;
#pragma unroll
    for (int it = 0; it < 8; ++it) {
      const int j = it * 256 + wave * 64 + lane;
      unsigned long long m = __ballot(row[j] != 0);
      if (lane < 2) {
        const int jw = it * 8 + wave * 2 + lane;
        pkT[(size_t)jw * V + i] = (unsigned int)(m >> (lane * 32));
      }
    }
    return;
  }

  // ---- proj block ----
  const int b = blockIdx.x >> 6;
  const int jt0 = blockIdx.x & 63;
  const int j0 = jt0 * 32;
  const int kq = lane >> 4, l15 = lane & 15;

  // phase -1: vL/vR = W^T aL/aR (redundant per block; W is L2-hot)
  {
    float sL = 0.f, sR = 0.f;
    for (int d = 0; d < D; ++d) {
      const float wv = W[(size_t)d * H + t];
      sL += wv * a[d];
      sR += wv * a[D + d];
    }
    vls[t] = sL;
    vrs[t] = sR;
  }
  __syncthreads();

  // phase 0: stage 8 rows per wave into f16 LDS; fp32 e-dots fused
  {
    const float4 vl4 = *(const float4*)(vls + lane * 4);
    const float4 vr4 = *(const float4*)(vrs + lane * 4);
#pragma unroll
    for (int rr = 0; rr < 8; ++rr) {
      const int row = wave * 8 + rr;
      const float4 xv = *(const float4*)(x + ((size_t)(b * V + j0 + row)) * H + lane * 4);
      uint32 u0 = pk2(xv.x, xv.y), u1 = pk2(xv.z, xv.w);
      const int off = row * 512 + ((lane * 8) ^ ((row & 7) << 4));
      *(uint32*)(xls + off) = u0;
      *(uint32*)(xls + off + 4) = u1;
      float eL = xv.x * vl4.x + xv.y * vl4.y + xv.z * vl4.z + xv.w * vl4.w;
      float eR = xv.x * vr4.x + xv.y * vr4.y + xv.z * vr4.z + xv.w * vr4.w;
#pragma unroll
      for (int off_ = 1; off_ < 64; off_ <<= 1) {
        eL += __shfl_xor(eL, off_, 64);
        eR += __shfl_xor(eR, off_, 64);
      }
      if (lane == 0) {
        const size_t r_ = (size_t)b * V + j0 + row;
        ei[r_] = eL;
        Fh[r_] = (_Float16)__expf(eR);
        Ph[r_] = (_Float16)__expf(0.2f * eR);
      }
    }
  }
  __syncthreads();

  // phase 1: GEMM; wave owns d rows [wave*32, wave*32+32); W fp32 -> pk2 inline
  f32x4 acc[2][2];
#pragma unroll
  for (int i_ = 0; i_ < 2; ++i_)
#pragma unroll
    for (int j_ = 0; j_ < 2; ++j_) acc[i_][j_] = (f32x4){0.f, 0.f, 0.f, 0.f};

  typedef union { uint32 u[4]; f16x8 v; } AFu_;
  const float* wrow0 = W + (size_t)(wave * 32 + l15) * H + kq * 8;
  const float* wrow1 = wrow0 + 16 * H;
#pragma unroll
  for (int ks = 0; ks < 8; ++ks) {
    const int ho = ks * 32;
    const float4 w0a = *(const float4*)(wrow0 + ho), w0b = *(const float4*)(wrow0 + ho + 4);
    const float4 w1a = *(const float4*)(wrow1 + ho), w1b = *(const float4*)(wrow1 + ho + 4);
    AFu_ aw0, aw1;
    aw0.u[0] = pk2(w0a.x, w0a.y); aw0.u[1] = pk2(w0a.z, w0a.w);
    aw0.u[2] = pk2(w0b.x, w0b.y); aw0.u[3] = pk2(w0b.z, w0b.w);
    aw1.u[0] = pk2(w1a.x, w1a.y); aw1.u[1] = pk2(w1a.z, w1a.w);
    aw1.u[2] = pk2(w1b.x, w1b.y); aw1.u[3] = pk2(w1b.z, w1b.w);
    f16x8 bx[2];
#pragma unroll
    for (int jt = 0; jt < 2; ++jt) {
      const int row = jt * 16 + l15;
      bx[jt] = *(const f16x8*)(xls + row * 512 + ((ks * 64 + kq * 16) ^ ((l15 & 7) << 4)));
    }
    acc[0][0] = __builtin_amdgcn_mfma_f32_16x16x32_f16(aw0.v, bx[0], acc[0][0], 0, 0, 0);
    acc[0][1] = __builtin_amdgcn_mfma_f32_16x16x32_f16(aw0.v, bx[1], acc[0][1], 0, 0, 0);
    acc[1][0] = __builtin_amdgcn_mfma_f32_16x16x32_f16(aw1.v, bx[0], acc[1][0], 0, 0, 0);
    acc[1][1] = __builtin_amdgcn_mfma_f32_16x16x32_f16(aw1.v, bx[1], acc[1][1], 0, 0, 0);
  }

  // C regs -> st[d][j]
#pragma unroll
  for (int t_ = 0; t_ < 2; ++t_)
#pragma unroll
    for (int jt = 0; jt < 2; ++jt)
#pragma unroll
      for (int r = 0; r < 4; ++r)
        st[(wave * 2 + t_) * 16 + kq * 4 + r][jt * 16 + l15] = (_Float16)acc[t_][jt][r];
  __syncthreads();

  // fragment store: pTf[b][c][dt][ks][lane][16B]
  const int c = jt0 >> 1;
  const int ksh = jt0 & 1;
  const int g = t >> 6;
#pragma unroll
  for (int ff = 0; ff < 2; ++ff) {
    const int dt = ff * 4 + g;
    const int dR = dt * 16 + l15;
    const int jc = kq * 8;
    union { unsigned long long ll[2]; f16x8 v; } vv_;
    vv_.ll[0] = *(const unsigned long long*)&st[dR][jc];
    vv_.ll[1] = *(const unsigned long long*)&st[dR][jc + 4];
    *(f16x8*)((char*)pTf +
              (((((size_t)b * 32 + c) * 8 + dt) * 2 + ksh) * 64 + lane) * 16) = vv_.v;
  }
}

// -------- K_attn: 32i x 32d waves; WGEN in native packed-f16 (no inline asm),
//          Eip-cancelled algebra: w' = max(r_i*F_j, P_j) * mask(2|0);
//          uniform factors (Eip_i, 2.0) cancel in the num/denom ratio. --------

typedef union { uint4 v; uint32 u[4]; } U4;
typedef union { uint32 u[4]; f16x8 v; } AFu;
struct PFS {
  U4 FH0, FH1, PH0, PH1;  // F/P tables, shared by both i-groups
  uint32 w[2][2];         // adj words [ig][ks]
  AFu AF[2][2];           // A fragments [ig][ks]
};

#define WGEN(S)                                                            \
  _Pragma("unroll") for (int ig_ = 0; ig_ < 2; ++ig_) {                    \
    const h2 R_ = R2h[ig_];                                                \
    _Pragma("unroll") for (int ks_ = 0; ks_ < 2; ++ks_) {                  \
      const uint32 sh_ = (S).w[ig_][ks_] >> kq8;                           \
      const U4& FH_ = ks_ ? (S).FH1 : (S).FH0;                             \
      const U4& PH_ = ks_ ? (S).PH1 : (S).PH0;                             \
      _Pragma("unroll") for (int p_ = 0; p_ < 4; ++p_) {                   \
        const h2 w_ = __builtin_elementwise_max(R_ * u2h(FH_.u[p_]),       \
                                                u2h(PH_.u[p_]));           \
        const uint32 m_ = ((sh_ << (14 - 2 * p_)) & 0x4000u) |             \
                          ((sh_ << (29 - 2 * p_)) & 0x40000000u);          \
        (S).AF[ig_][ks_].u[p_] = h2u(w_ * u2h(m_));                        \
      }                                                                    \
    }                                                                      \
  }

#define PFETCH(S, C)                                       \
  {                                                        \
    const char* f_ = fbase + (C) * 128 + kq16;             \
    const char* p_ = pbase + (C) * 128 + kq16;             \
    (S).FH0.v = *(const uint4*)(f_);                       \
    (S).FH1.v = *(const uint4*)(f_ + 64);                  \
    (S).PH0.v = *(const uint4*)(p_);                       \
    (S).PH1.v = *(const uint4*)(p_ + 64);                  \
    (S).w[0][0] = adjpT[(size_t)((C) * 2) * V + iR0];      \
    (S).w[0][1] = adjpT[(size_t)((C) * 2 + 1) * V + iR0];  \
    (S).w[1][0] = adjpT[(size_t)((C) * 2) * V + iR1];      \
    (S).w[1][1] = adjpT[(size_t)((C) * 2 + 1) * V + iR1];  \
  }

#define LOADB(BR, C)                                      \
  {                                                       \
    const char* g_ = gbase + (size_t)(C) * 16384;         \
    _Pragma("unroll") for (int q_ = 0; q_ < 4; ++q_)      \
      BR[q_] = *(const f16x8*)(g_ + q_ * 1024);           \
  }

#define DOMFMA(S, BX)                                                          \
  _Pragma("unroll") for (int ig_ = 0; ig_ < 2; ++ig_)                          \
    _Pragma("unroll") for (int nt_ = 0; nt_ < 2; ++nt_)                        \
      _Pragma("unroll") for (int ks_ = 0; ks_ < 2; ++ks_)                      \
        acc[ig_][nt_][ks_] = __builtin_amdgcn_mfma_f32_16x16x32_f16(           \
            (S).AF[ig_][ks_].v, BX[nt_ * 2 + ks_], acc[ig_][nt_][ks_], 0, 0, 0); \
  _Pragma("unroll") for (int ig_ = 0; ig_ < 2; ++ig_)                          \
    _Pragma("unroll") for (int ks_ = 0; ks_ < 2; ++ks_)                        \
      accS[ig_][ks_] = __builtin_amdgcn_mfma_f32_16x16x32_f16(                 \
          (S).AF[ig_][ks_].v, onesv, accS[ig_][ks_], 0, 0, 0);

#define BODYF(C, SX, BX, SY)   \
  {                            \
    DOMFMA(SX, BX)             \
    WGEN(SY)                   \
    LOADB(BX, (C) + 2)         \
    PFETCH(SX, (C) + 2)        \
  }

__global__ __launch_bounds__(256, 2) void k_attn(
    const _Float16* __restrict__ pTf,
    const float* __restrict__ ei,
    const _Float16* __restrict__ Fht,
    const _Float16* __restrict__ Pht,
    const unsigned int* __restrict__ adjpT,
    float* __restrict__ out) {
  const int t = threadIdx.x, lane = t & 63, wave = t >> 6;
  const int ih = wave >> 1;
  const int dq = wave & 1;
  // bijective XCD chunk swizzle (nwg=512, 64 per XCD)
  const int pay = (blockIdx.x & 7) * 64 + (blockIdx.x >> 3);
  const int bdh = pay >> 4;
  const int itl = pay & 15;
  const int b = bdh >> 2, dh = (bdh >> 1) & 1;
  const int it = ((bdh & 1) << 4) | itl;
  const int i0b = it * 64;
  const int kq = lane >> 4;
  const int kq8 = kq * 8;
  const int kq16 = kq * 16;
  const int l15 = lane & 15;
  const int ibase = i0b + ih * 32;
  const int iR0 = ibase + l15;
  const int iR1 = iR0 + 16;

  const float eiv0 = ei[(size_t)b * V + iR0];
  const float eiv1 = ei[(size_t)b * V + iR1];
  h2 R2h[2];
  {
    // Eip-cancellation: r_i = Ei/Eip = exp(0.8*e_i); Eip and the mask's 2.0
    // are uniform factors on all surviving elements -> cancel in the ratio.
    const float r0 = __expf(0.8f * eiv0), r1 = __expf(0.8f * eiv1);
    R2h[0] = u2h(pk2(r0, r0));
    R2h[1] = u2h(pk2(r1, r1));
  }
  const char* fbase = (const char*)(Fht + (size_t)b * V);
  const char* pbase = (const char*)(Pht + (size_t)b * V);
  const size_t fb0 = ((size_t)b * 32) * 16384 + (size_t)dh * 8192;
  const char* gbase = (const char*)pTf + fb0 + dq * 4096 + lane * 16;

  union { uint32 u[4]; f16x8 v; } ones_;
  ones_.u[0] = ones_.u[1] = ones_.u[2] = ones_.u[3] = 0x3C003C00u;
  const f16x8 onesv = ones_.v;

  f32x4 acc[2][2][2];
#pragma unroll
  for (int a_ = 0; a_ < 2; ++a_)
#pragma unroll
    for (int b_ = 0; b_ < 2; ++b_)
#pragma unroll
      for (int c_ = 0; c_ < 2; ++c_) acc[a_][b_][c_] = (f32x4){0.f, 0.f, 0.f, 0.f};
  f32x4 accS[2][2];
#pragma unroll
  for (int a_ = 0; a_ < 2; ++a_)
#pragma unroll
    for (int c_ = 0; c_ < 2; ++c_) accS[a_][c_] = (f32x4){0.f, 0.f, 0.f, 0.f};

  f16x8 bA[4], bB[4];
  PFS sA, sB;

  LOADB(bA, 0)
  LOADB(bB, 1)
  PFETCH(sA, 0)
  PFETCH(sB, 1)
  WGEN(sA)

  for (int c2 = 0; c2 < 15; ++c2) {
    const int c = c2 * 2;
    BODYF(c, sA, bA, sB)
    BODYF(c + 1, sB, bB, sA)
  }
  {
    DOMFMA(sA, bA)
    WGEN(sB)
  }
  { DOMFMA(sB, bB) }

  float* ob = out + ((size_t)b * V + ibase) * D + dh * 64 + dq * 32 + l15;
#pragma unroll
  for (int ig = 0; ig < 2; ++ig) {
#pragma unroll
    for (int r = 0; r < 4; ++r) {
      const float inv_ = 1.0f / (accS[ig][0][r] + accS[ig][1][r]);
#pragma unroll
      for (int nt = 0; nt < 2; ++nt) {
        const float v = (acc[ig][nt][0][r] + acc[ig][nt][1][r]) * inv_;
        ob[(size_t)(ig * 16 + kq * 4 + r) * D + nt * 16] = fmaxf(v, 0.f);
      }
    }
  }
}

extern "C" void kernel_launch(void* const* d_in, const int* in_sizes, int n_in,
                              void* d_out, int out_size, void* d_ws, size_t ws_size,
                              hipStream_t stream) {
  const float* x = (const float*)d_in[0];
  const int* adj = (const int*)d_in[1];
  const float* W = (const float*)d_in[2];
  const float* a = (const float*)d_in[3];
  float* out = (float*)d_out;

  char* ws = (char*)d_ws;
  _Float16* pTf = (_Float16*)ws;                                   // 4 MB
  float* ei = (float*)(ws + (4u << 20));                           // 64 KB
  _Float16* Fh = (_Float16*)(ws + (4u << 20) + 65536);             // 32 KB
  _Float16* Ph = (_Float16*)(ws + (4u << 20) + 98304);             // 32 KB
  unsigned int* adjpT = (unsigned int*)(ws + (4u << 20) + 131072); // 512 KB

  k_prep<<<dim3(NPROJ + V), dim3(256), 0, stream>>>(x, adj, W, a, pTf, ei, Fh, Ph, adjpT);
  k_attn<<<dim3(BATCH * 2 * (V / 64)), dim3(256), 0, stream>>>(pTf, ei, Fh, Ph, adjpT, out);
}